// Round 6
// baseline (536.054 us; speedup 1.0000x reference)
//
#include <hip/hip_runtime.h>

typedef __attribute__((ext_vector_type(4))) unsigned short u16x4;
typedef __attribute__((ext_vector_type(8))) short short8;
typedef __attribute__((ext_vector_type(4))) short short4b;
typedef __attribute__((ext_vector_type(4))) float f32x4;

__device__ inline unsigned short f2bf(float f) {
    union { float f; unsigned int i; } v; v.f = f;
    unsigned int r = v.i + 0x7fffu + ((v.i >> 16) & 1u);
    return (unsigned short)(r >> 16);
}

#define MFMA_PV(a, b, c) __builtin_amdgcn_mfma_f32_16x16x16bf16_1k((a), (b), (c), 0, 0, 0)
#define MFMA32(a, b, c) __builtin_amdgcn_mfma_f32_16x16x32_bf16((a), (b), (c), 0, 0, 0)

__device__ inline void gload_lds16(const unsigned short* g, unsigned short* l) {
    __builtin_amdgcn_global_load_lds(
        (const __attribute__((address_space(1))) void*)g,
        (__attribute__((address_space(3))) void*)l,
        16, 0, 0);
}

// ---------------------------------------------------------------------------
// f32 -> bf16 elementwise convert
// ---------------------------------------------------------------------------
__global__ __launch_bounds__(256) void convert_f32_bf16(const float* __restrict__ in,
                                                        unsigned short* __restrict__ out,
                                                        int n4) {
    int i = blockIdx.x * 256 + threadIdx.x;
    if (i >= n4) return;
    float4 v = ((const float4*)in)[i];
    u16x4 o = { f2bf(v.x), f2bf(v.y), f2bf(v.z), f2bf(v.w) };
    ((u16x4*)out)[i] = o;
}

// ---------------------------------------------------------------------------
// 4 weight transposes fused: out_bf16[n][k] = in_f32[k][n], 1024x1024 each
// grid (32, 32, 4)
// ---------------------------------------------------------------------------
__global__ __launch_bounds__(256) void transpose_w4(const float* __restrict__ W0,
                                                    const float* __restrict__ W1,
                                                    const float* __restrict__ W2,
                                                    const float* __restrict__ W3,
                                                    unsigned short* __restrict__ O0,
                                                    unsigned short* __restrict__ O1,
                                                    unsigned short* __restrict__ O2,
                                                    unsigned short* __restrict__ O3) {
    __shared__ unsigned short tile[32][33];
    const float* in = (blockIdx.z == 0) ? W0 : (blockIdx.z == 1) ? W1
                    : (blockIdx.z == 2) ? W2 : W3;
    unsigned short* out = (blockIdx.z == 0) ? O0 : (blockIdx.z == 1) ? O1
                        : (blockIdx.z == 2) ? O2 : O3;
    int c0 = blockIdx.x * 32, r0 = blockIdx.y * 32;
    int x = threadIdx.x & 31, y = threadIdx.x >> 5;
#pragma unroll
    for (int i = 0; i < 4; i++)
        tile[y + i * 8][x] = f2bf(in[(size_t)(r0 + y + i * 8) * 1024 + c0 + x]);
    __syncthreads();
#pragma unroll
    for (int i = 0; i < 4; i++)
        out[(size_t)(c0 + y + i * 8) * 1024 + r0 + x] = tile[x][y + i * 8];
}

// ---------------------------------------------------------------------------
// GEMM (m97 structure + T2 via pre-swizzled source).
// Out[m][n] = sum_k X[m][k]*Wt[n][k] + bias[n].
// F32OUT: nontemporal f32 out. KTILED/VTILED: write attn tile layouts.
// ---------------------------------------------------------------------------
template <int F32OUT, int KTILED, int VTILED>
__global__ __launch_bounds__(256) void gemm_bt(const unsigned short* __restrict__ X,
                                               const unsigned short* __restrict__ Wt,
                                               const float* __restrict__ bias,
                                               void* __restrict__ outp,
                                               int M, int N, int K) {
    __shared__ unsigned short As[128 * 64];
    __shared__ unsigned short Bs[128 * 64];
    const int t = threadIdx.x;
    const int l = t & 63, w = t >> 6;
    const int lg = l >> 4, ln = l & 15;
    const int wm = (w >> 1) * 64, wn = (w & 1) * 64;
    const int m0 = blockIdx.y * 128, n0 = blockIdx.x * 128;

    const f32x4 zero = {0.f, 0.f, 0.f, 0.f};
    f32x4 acc[4][4];
#pragma unroll
    for (int i = 0; i < 4; i++)
#pragma unroll
        for (int j = 0; j < 4; j++) acc[i][j] = zero;

    int sr[4], sc[4];
#pragma unroll
    for (int i = 0; i < 4; i++) {
        int pos = i * 2048 + t * 8;
        sr[i] = pos >> 6;
        int c8 = (pos >> 3) & 7;
        sc[i] = (c8 ^ (sr[i] & 7)) * 8;
    }

    for (int k0 = 0; k0 < K; k0 += 64) {
#pragma unroll
        for (int i = 0; i < 4; i++)
            gload_lds16(&X[(size_t)(m0 + sr[i]) * K + k0 + sc[i]], &As[i * 2048 + w * 512]);
#pragma unroll
        for (int i = 0; i < 4; i++)
            gload_lds16(&Wt[(size_t)(n0 + sr[i]) * K + k0 + sc[i]], &Bs[i * 2048 + w * 512]);
        __syncthreads();
#pragma unroll
        for (int kk = 0; kk < 2; kk++) {
            short8 af[4], bfr[4];
#pragma unroll
            for (int i = 0; i < 4; i++) {
                int sl = (((kk << 2) | lg) ^ (ln & 7)) * 8;
                af[i]  = *(const short8*)&As[(wm + i * 16 + ln) * 64 + sl];
                bfr[i] = *(const short8*)&Bs[(wn + i * 16 + ln) * 64 + sl];
            }
#pragma unroll
            for (int i = 0; i < 4; i++)
#pragma unroll
                for (int j = 0; j < 4; j++)
                    acc[i][j] = MFMA32(af[i], bfr[j], acc[i][j]);
        }
        __syncthreads();
    }

#pragma unroll
    for (int j = 0; j < 4; j++) {
        int gn = n0 + wn + j * 16 + ln;
        float bvv = bias[gn];
#pragma unroll
        for (int i = 0; i < 4; i++) {
            int gm = m0 + wm + i * 16 + 4 * lg;
#pragma unroll
            for (int jj = 0; jj < 4; jj++) {
                float val = acc[i][j][jj] + bvv;
                int m = gm + jj, n = gn;
                if (F32OUT) {
                    __builtin_nontemporal_store(val, &((float*)outp)[(size_t)m * N + n]);
                } else if (KTILED) {
                    int b = m >> 11, s = m & 2047;
                    int itk = s >> 5, r = s & 31;
                    int h = n >> 6, dl = n & 63;
                    int cst = (dl >> 3) ^ (r & 7);
                    size_t off = (size_t)(b * 16 + h) * 131072 +
                                 (size_t)itk * 2048 + r * 64 + cst * 8 + (dl & 7);
                    ((unsigned short*)outp)[off] = f2bf(val);
                } else if (VTILED) {
                    int b = m >> 11, s = m & 2047;
                    int h = n >> 6, dl = n & 63;
                    size_t off = (size_t)(b * 16 + h) * 131072 +
                                 (size_t)(s >> 5) * 2048 + ((s >> 4) & 1) * 1024 +
                                 dl * 16 + (s & 15);
                    ((unsigned short*)outp)[off] = f2bf(val);
                } else {
                    ((unsigned short*)outp)[(size_t)m * N + n] = f2bf(val);
                }
            }
        }
    }
}

// ---------------------------------------------------------------------------
// attn pass 1: softmax denominators. Block = (b,h) x 128 q-rows (2 sets of
// 64; wave w owns rows w*16.. of each set). KVBLK=64 double-buffered.
// ---------------------------------------------------------------------------
__global__ __launch_bounds__(256) void attn_pass1(const unsigned short* __restrict__ Qp,
                                                  const unsigned short* __restrict__ Kt,
                                                  float* __restrict__ se_buf) {
    const int S = 2048, Dm = 1024;
    __shared__ unsigned short Ks[2][4096];

    int blk = blockIdx.x;
    int wid = (blk & 7) * 128 + (blk >> 3);
    int qt = wid & 15, bh = wid >> 4;
    int b = bh >> 4, h = bh & 15;
    int t = threadIdx.x, l = t & 63, w = t >> 6;
    int lg = l >> 4, ln = l & 15;
    int qbase = qt * 128 + w * 16;

    const unsigned short* Qr0 = Qp + (size_t)(b * S + qbase + ln) * Dm + h * 64;
    const unsigned short* Qr1 = Qr0 + (size_t)64 * Dm;
    short8 q00 = *(const short8*)&Qr0[8 * lg];
    short8 q01 = *(const short8*)&Qr0[32 + 8 * lg];
    short8 q10 = *(const short8*)&Qr1[8 * lg];
    short8 q11 = *(const short8*)&Qr1[32 + 8 * lg];

    const unsigned short* Kb = Kt + (size_t)bh * 131072;
    const int c0x = (lg ^ (ln & 7)) * 8;
    const int c1x = ((4 + lg) ^ (ln & 7)) * 8;
    const int gb[4] = { ln * 64, 1024 + ln * 64, 2048 + ln * 64, 3072 + ln * 64 };

#define STAGE_K64(it, buf) do { \
    gload_lds16(Kb + (size_t)(it) * 4096 + t * 8, &Ks[buf][w * 512]); \
    gload_lds16(Kb + (size_t)(it) * 4096 + 2048 + t * 8, &Ks[buf][2048 + w * 512]); } while (0)

    const f32x4 zero = {0.f, 0.f, 0.f, 0.f};
    float se0 = 0.f, se1 = 0.f;
    int cur = 0;
    STAGE_K64(0, 0);
    __syncthreads();
    for (int it = 0; it < 32; ++it) {
        if (it < 31) STAGE_K64(it + 1, cur ^ 1);
        f32x4 s0[4], s1[4];
        __builtin_amdgcn_s_setprio(1);
#pragma unroll
        for (int g = 0; g < 4; g++) {
            short8 ka = *(const short8*)&Ks[cur][gb[g] + c0x];
            short8 kb = *(const short8*)&Ks[cur][gb[g] + c1x];
            s0[g] = MFMA32(ka, q00, zero);
            s0[g] = MFMA32(kb, q01, s0[g]);
            s1[g] = MFMA32(ka, q10, zero);
            s1[g] = MFMA32(kb, q11, s1[g]);
        }
        __builtin_amdgcn_s_setprio(0);
#pragma unroll
        for (int g = 0; g < 4; g++) {
#pragma unroll
            for (int j = 0; j < 4; j++) {
                se0 += __expf(s0[g][j] * 0.125f);
                se1 += __expf(s1[g][j] * 0.125f);
            }
        }
        __syncthreads();
        cur ^= 1;
    }
    se0 += __shfl_xor(se0, 16); se0 += __shfl_xor(se0, 32);
    se1 += __shfl_xor(se1, 16); se1 += __shfl_xor(se1, 32);
    if (lg == 0) {
        se_buf[bh * 2048 + qbase + ln] = se0;
        se_buf[bh * 2048 + qbase + 64 + ln] = se1;
    }
#undef STAGE_K64
}

// ---------------------------------------------------------------------------
// attn pass 2: recompute scores, write attn (f32, nontemporal), PV.
// Block = (b,h) x 128 q-rows (2 sets). KVBLK=64 double-buffered K+V.
// ---------------------------------------------------------------------------
__global__ __launch_bounds__(256) void attn_pass2(const unsigned short* __restrict__ Qp,
                                                  const unsigned short* __restrict__ Kt,
                                                  const unsigned short* __restrict__ Vt,
                                                  const float* __restrict__ se_buf,
                                                  float* __restrict__ attn_out,
                                                  unsigned short* __restrict__ Ctx) {
    const int S = 2048, Dm = 1024;
    __shared__ unsigned short Ks[2][4096];
    __shared__ unsigned short Vs[2][4096];

    int blk = blockIdx.x;
    int wid = (blk & 7) * 128 + (blk >> 3);
    int qt = wid & 15, bh = wid >> 4;
    int b = bh >> 4, h = bh & 15;
    int t = threadIdx.x, l = t & 63, w = t >> 6;
    int lg = l >> 4, ln = l & 15;
    int qbase = qt * 128 + w * 16;

    const unsigned short* Qr0 = Qp + (size_t)(b * S + qbase + ln) * Dm + h * 64;
    const unsigned short* Qr1 = Qr0 + (size_t)64 * Dm;
    short8 q00 = *(const short8*)&Qr0[8 * lg];
    short8 q01 = *(const short8*)&Qr0[32 + 8 * lg];
    short8 q10 = *(const short8*)&Qr1[8 * lg];
    short8 q11 = *(const short8*)&Qr1[32 + 8 * lg];

    float inv0 = 1.0f / se_buf[bh * 2048 + qbase + ln];
    float inv1 = 1.0f / se_buf[bh * 2048 + qbase + 64 + ln];

    const unsigned short* Kb = Kt + (size_t)bh * 131072;
    const unsigned short* Vb = Vt + (size_t)bh * 131072;
    const int c0x = (lg ^ (ln & 7)) * 8;
    const int c1x = ((4 + lg) ^ (ln & 7)) * 8;
    const int gb[4] = { ln * 64, 1024 + ln * 64, 2048 + ln * 64, 3072 + ln * 64 };

#define STAGE_K64(it, buf) do { \
    gload_lds16(Kb + (size_t)(it) * 4096 + t * 8, &Ks[buf][w * 512]); \
    gload_lds16(Kb + (size_t)(it) * 4096 + 2048 + t * 8, &Ks[buf][2048 + w * 512]); } while (0)
#define STAGE_V64(it, buf) do { \
    gload_lds16(Vb + (size_t)(it) * 4096 + t * 8, &Vs[buf][w * 512]); \
    gload_lds16(Vb + (size_t)(it) * 4096 + 2048 + t * 8, &Vs[buf][2048 + w * 512]); } while (0)

    const f32x4 zero = {0.f, 0.f, 0.f, 0.f};
    f32x4 acc0[4], acc1[4];
#pragma unroll
    for (int i = 0; i < 4; i++) { acc0[i] = zero; acc1[i] = zero; }

    float* Ar0 = attn_out + ((size_t)bh * S + qbase + ln) * S;
    float* Ar1 = Ar0 + (size_t)64 * S;

    int cur = 0;
    STAGE_K64(0, 0);
    STAGE_V64(0, 0);
    __syncthreads();
    for (int it = 0; it < 32; ++it) {
        if (it < 31) { STAGE_K64(it + 1, cur ^ 1); STAGE_V64(it + 1, cur ^ 1); }
        f32x4 s0[4], s1[4];
        __builtin_amdgcn_s_setprio(1);
#pragma unroll
        for (int g = 0; g < 4; g++) {
            short8 ka = *(const short8*)&Ks[cur][gb[g] + c0x];
            short8 kb = *(const short8*)&Ks[cur][gb[g] + c1x];
            s0[g] = MFMA32(ka, q00, zero);
            s0[g] = MFMA32(kb, q01, s0[g]);
            s1[g] = MFMA32(ka, q10, zero);
            s1[g] = MFMA32(kb, q11, s1[g]);
        }
        __builtin_amdgcn_s_setprio(0);

        union { short4b v; unsigned short u[4]; } pf0[4], pf1[4];
#pragma unroll
        for (int g = 0; g < 4; g++) {
            f32x4 pw0, pw1;
#pragma unroll
            for (int j = 0; j < 4; j++) {
                float p0 = __expf(s0[g][j] * 0.125f) * inv0;
                float p1 = __expf(s1[g][j] * 0.125f) * inv1;
                pw0[j] = p0; pf0[g].u[j] = f2bf(p0);
                pw1[j] = p1; pf1[g].u[j] = f2bf(p1);
            }
            __builtin_nontemporal_store(pw0, (f32x4*)&Ar0[it * 64 + g * 16 + 4 * lg]);
            __builtin_nontemporal_store(pw1, (f32x4*)&Ar1[it * 64 + g * 16 + 4 * lg]);
        }

        __builtin_amdgcn_s_setprio(1);
#pragma unroll
        for (int db = 0; db < 4; db++) {
            int vbase = (db * 16 + ln) * 16 + 4 * lg;
#pragma unroll
            for (int g = 0; g < 4; g++) {
                short4b vf = *(const short4b*)&Vs[cur][g * 1024 + vbase];
                acc0[db] = MFMA_PV(pf0[g].v, vf, acc0[db]);
                acc1[db] = MFMA_PV(pf1[g].v, vf, acc1[db]);
            }
        }
        __builtin_amdgcn_s_setprio(0);
        __syncthreads();
        cur ^= 1;
    }

    // ctx: lane reg j holds (q = qbase + set*64 + 4*lg + j, d = db*16 + ln)
#pragma unroll
    for (int db = 0; db < 4; db++)
#pragma unroll
        for (int j = 0; j < 4; j++) {
            Ctx[(size_t)(b * S + qbase + 4 * lg + j) * Dm + h * 64 + db * 16 + ln] =
                f2bf(acc0[db][j]);
            Ctx[(size_t)(b * S + qbase + 64 + 4 * lg + j) * Dm + h * 64 + db * 16 + ln] =
                f2bf(acc1[db][j]);
        }
#undef STAGE_K64
#undef STAGE_V64
}

// ---------------------------------------------------------------------------
extern "C" void kernel_launch(void* const* d_in, const int* in_sizes, int n_in,
                              void* d_out, int out_size, void* d_ws, size_t ws_size,
                              hipStream_t stream) {
    const float* query = (const float*)d_in[0];
    const float* key_  = (const float*)d_in[1];
    const float* value = (const float*)d_in[2];
    const float* Wq = (const float*)d_in[4];
    const float* bq = (const float*)d_in[5];
    const float* Wk = (const float*)d_in[6];
    const float* bk = (const float*)d_in[7];
    const float* Wv = (const float*)d_in[8];
    const float* bv = (const float*)d_in[9];
    const float* Wo = (const float*)d_in[10];
    const float* bo = (const float*)d_in[11];

    const size_t BSD = (size_t)4 * 2048 * 1024;
    const size_t DD  = (size_t)1024 * 1024;

    unsigned short* Xbuf = (unsigned short*)d_ws;   // bf16 input / later Ctx
    unsigned short* Qp  = Xbuf + BSD;
    unsigned short* Kt  = Qp + BSD;                 // K tiled+swizzled
    unsigned short* Vt  = Kt + BSD;                 // V tiled
    unsigned short* WqT = Vt + BSD;
    unsigned short* WkT = WqT + DD;
    unsigned short* WvT = WkT + DD;
    unsigned short* WoT = WvT + DD;
    float* SE = (float*)(WoT + DD);                 // 64*2048 f32
    unsigned short* Ctx = Xbuf;

    float* out0 = (float*)d_out;                    // [B,S,D] f32
    float* attn = out0 + BSD;                       // [B,H,S,S] f32

    dim3 tb(256);
    int n4 = (int)(BSD / 4);
    dim3 cg((n4 + 255) / 256);

    transpose_w4<<<dim3(32, 32, 4), tb, 0, stream>>>(Wq, Wk, Wv, Wo, WqT, WkT, WvT, WoT);

    convert_f32_bf16<<<cg, tb, 0, stream>>>(query, Xbuf, n4);
    gemm_bt<0, 0, 0><<<dim3(8, 64), tb, 0, stream>>>(Xbuf, WqT, bq, Qp, 8192, 1024, 1024);

    convert_f32_bf16<<<cg, tb, 0, stream>>>(key_, Xbuf, n4);
    gemm_bt<0, 1, 0><<<dim3(8, 64), tb, 0, stream>>>(Xbuf, WkT, bk, Kt, 8192, 1024, 1024);

    attn_pass1<<<dim3(1024), tb, 0, stream>>>(Qp, Kt, SE);

    convert_f32_bf16<<<cg, tb, 0, stream>>>(value, Xbuf, n4);
    gemm_bt<0, 0, 1><<<dim3(8, 64), tb, 0, stream>>>(Xbuf, WvT, bv, Vt, 8192, 1024, 1024);

    attn_pass2<<<dim3(1024), tb, 0, stream>>>(Qp, Kt, Vt, SE, attn, Ctx);

    gemm_bt<1, 0, 0><<<dim3(8, 64), tb, 0, stream>>>(Ctx, WoT, bo, out0, 8192, 1024, 1024);
}